// Round 11
// baseline (1110.236 us; speedup 1.0000x reference)
//
#include <hip/hip_runtime.h>
#include <hip/hip_bf16.h>
#include <math.h>

// ---------------------------------------------------------------------------
// DNC forward on MI355X — spill-free consumer via single-copy link + LDS
// transpose staging.
//   k_main: 128 blocks x 512 threads.
//     blocks 0-63  (producers): LSTM waves 0-3 + xi GEMM waves 4-7 (t-2),
//       34 flag-lockstepped phases (hidden under consumer).
//     blocks 64-127 (consumers): DNC memory recurrence, 1 block/batch.
//       Register diet (compiler gives 128 VGPR at 512thr; r4 design needed
//       160+ -> spilled, r7-r10 proved spills = dominant cost):
//       - ONE link copy in registers (row-major, 64 VGPR); col-copy dropped.
//       - bwd = L^T rw via 8 sub-phases: stage 32 updated rows into a 16.5KB
//         LDS buffer (union-aliased onto per-step-dead scratch), MFMA with
//         transposed-fragment reads.
//       - memory rows kept in smem only (mr registers dropped).
//   k_tanhy / k_out unchanged.
// ---------------------------------------------------------------------------

typedef __bf16 bf16_t;
typedef __attribute__((ext_vector_type(8))) __bf16 bf16x8;
typedef __attribute__((ext_vector_type(4))) float f32x4;

#define B_    64
#define T_    32
#define IN_   256
#define H_    512
#define M_    256
#define W_    64
#define R_    4
#define IFACE_ 471
#define DELTA_ 1e-6f

// ---------------- ws layout (bytes) ----------------
#define OFF_H0SEQ  (0L)
#define SZ_H0SEQ   (32L*64*512*2)
#define OFF_OUTSEQ (OFF_H0SEQ + SZ_H0SEQ)
#define SZ_OUTSEQ  (32L*64*512*2)
#define OFF_H0BUF  (OFF_OUTSEQ + SZ_OUTSEQ)
#define SZ_HBUF    (2L*64*512*2)
#define OFF_H1BUF  (OFF_H0BUF + SZ_HBUF)
#define OFF_XI     (OFF_H1BUF + SZ_HBUF)
#define SZ_XI      (32L*64*480*4)
#define OFF_RVEC   (OFF_XI + SZ_XI)
#define SZ_RVEC    (32L*64*256*4)
#define OFF_YBF    (OFF_RVEC + SZ_RVEC)
#define SZ_YBF     (32L*64*768*2)
#define OFF_BAR    (OFF_YBF + SZ_YBF)
#define SZ_BAR     (256L)
#define OFF_XB     (OFF_BAR + SZ_BAR)
#define SZ_XB      (64L*32*256*2)
#define OFF_H0B    (OFF_XB + SZ_XB)
#define SZ_H0B     (2L*64*512*2)
#define OFF_W0     (OFF_H0B + SZ_H0B)
#define SZ_W       (2048L*512*2)
#define OFF_W1     (OFF_W0 + SZ_W)
#define OFF_W2     (OFF_W1 + SZ_W)
#define OFF_W3     (OFF_W2 + SZ_W)
#define OFF_WIF    (OFF_W3 + SZ_W)
#define SZ_WIF     (480L*512*2)
#define OFF_WOUTB  (OFF_WIF + SZ_WIF)
#define SZ_WOUTB   (256L*768*2)
#define OFF_BS0    (OFF_WOUTB + SZ_WOUTB)
#define SZ_BS      (2048L*4)
#define OFF_BS1    (OFF_BS0 + SZ_BS)
#define OFF_BIF    (OFF_BS1 + SZ_BS)
#define SZ_BIF     (2048L)
#define OFF_BOUTF  (OFF_BIF + SZ_BIF)
#define SZ_BOUTF   (1024L)
#define OFF_FLG    (OFF_BOUTF + SZ_BOUTF)
#define SZ_FLG     (4096L)                // 64 per-block flags, 64B apart

// ---- fast native math ----
__device__ __forceinline__ float frcp(float x){ return __builtin_amdgcn_rcpf(x); }
__device__ __forceinline__ float fsqrt_(float x){ return __builtin_amdgcn_sqrtf(x); }
__device__ __forceinline__ float sigf(float x){ return frcp(1.0f + __expf(-x)); }
__device__ __forceinline__ float tanh_f(float x){
  float xc = fminf(fmaxf(x, -44.0f), 44.0f);
  float t = __expf(2.0f * xc);
  return (t - 1.0f) * frcp(t + 1.0f);
}
__device__ __forceinline__ float softplusf(float x){
  return fmaxf(x, 0.0f) + __logf(1.0f + __expf(-fabsf(x)));
}
__device__ __forceinline__ float wred(float v){
  #pragma unroll
  for (int off = 32; off; off >>= 1) v += __shfl_xor(v, off, 64);
  return v;
}
__device__ __forceinline__ float ldin(const void* p, long i, int mf){
  return mf ? ((const float*)p)[i] : (float)((const bf16_t*)p)[i];
}

__device__ __forceinline__ unsigned flag_ld(const unsigned* p){
  return __hip_atomic_load(p, __ATOMIC_RELAXED, __HIP_MEMORY_SCOPE_AGENT);
}

// producer phase barrier: release store + wave-0 relaxed poll + acquire fence.
__device__ __forceinline__ void flagbar(unsigned* flg, int bid, unsigned tgt,
                                        int tid, int lane, int wv){
  __syncthreads();
  if (tid == 0)
    __hip_atomic_store(flg + (size_t)bid*16, tgt, __ATOMIC_RELEASE,
                       __HIP_MEMORY_SCOPE_AGENT);
  if (wv == 0){
    for (;;){
      unsigned f = flag_ld(flg + (size_t)lane*16);
      if (__all(f >= tgt)) break;
      __builtin_amdgcn_s_sleep(2);
    }
    __builtin_amdgcn_fence(__ATOMIC_ACQUIRE, "agent");
  }
  __syncthreads();
}

// ---------------------------------------------------------------------------
__global__ void k_detect(const unsigned short* __restrict__ x16,
                         int* __restrict__ flag, unsigned* __restrict__ bar,
                         unsigned* __restrict__ flg){
  __shared__ int cnt;
  if (threadIdx.x == 0){ cnt = 0; bar[0] = 0u; bar[1] = 0u; }
  for (int i = threadIdx.x; i < 1024; i += 256) flg[i] = 0u;
  __syncthreads();
  unsigned short u = x16[threadIdx.x * 2];
  int e = (u >> 7) & 0xFF;
  if (e >= 0x88) atomicAdd(&cnt, 1);
  __syncthreads();
  if (threadIdx.x == 0) *flag = (cnt > 16) ? 1 : 0;
}

// ---------------------------------------------------------------------------
__global__ void k_convert(const void* x, const void* h0, const void* Wih0,
                          const void* Whh0, const void* bih0, const void* bhh0,
                          const void* Wih1, const void* Whh1, const void* bih1,
                          const void* bhh1, const void* Wif, const void* bif,
                          const void* Wout, const void* bout,
                          bf16_t* __restrict__ xb, bf16_t* __restrict__ h0b,
                          bf16_t* __restrict__ h0buf, bf16_t* __restrict__ h1buf,
                          bf16_t* __restrict__ W0, bf16_t* __restrict__ W1,
                          bf16_t* __restrict__ W2, bf16_t* __restrict__ W3,
                          bf16_t* __restrict__ Wifp, bf16_t* __restrict__ Woutb,
                          float* __restrict__ bs0, float* __restrict__ bs1,
                          float* __restrict__ bifp, float* __restrict__ boutf,
                          const int* __restrict__ flag)
{
  const int mf = *flag;
  const long stride = (long)gridDim.x * blockDim.x;
  long i0 = (long)blockIdx.x * blockDim.x + threadIdx.x;
  switch (blockIdx.y){
  case 0: for (long i = i0; i < 64L*32*256; i += stride) xb[i] = (bf16_t)ldin(x, i, mf); break;
  case 1: for (long i = i0; i < 2L*64*512; i += stride){
            float v = ldin(h0, i, mf); bf16_t bb = (bf16_t)v; h0b[i] = bb;
            if (i < 64*512) h0buf[i] = bb; else h1buf[i - 64*512] = bb;
          } break;
  case 2: for (long i = i0; i < 2048L*512; i += stride) W0[i] = (bf16_t)ldin(Wih0, i, mf); break;
  case 3: for (long i = i0; i < 2048L*512; i += stride) W1[i] = (bf16_t)ldin(Whh0, i, mf); break;
  case 4: for (long i = i0; i < 2048L*512; i += stride) W2[i] = (bf16_t)ldin(Wih1, i, mf); break;
  case 5: for (long i = i0; i < 2048L*512; i += stride) W3[i] = (bf16_t)ldin(Whh1, i, mf); break;
  case 6: for (long i = i0; i < 480L*512; i += stride){
            long r = i >> 9;
            Wifp[i] = (r < IFACE_) ? (bf16_t)ldin(Wif, i, mf) : (bf16_t)0.0f;
          } break;
  case 7: for (long i = i0; i < 256L*768; i += stride) Woutb[i] = (bf16_t)ldin(Wout, i, mf); break;
  case 8:
    for (long i = i0; i < 2048; i += stride){
      bs0[i] = ldin(bih0, i, mf) + ldin(bhh0, i, mf);
      bs1[i] = ldin(bih1, i, mf) + ldin(bhh1, i, mf);
    }
    for (long i = i0; i < 480; i += stride) bifp[i] = (i < IFACE_) ? ldin(bif, i, mf) : 0.0f;
    for (long i = i0; i < 256; i += stride) boutf[i] = ldin(bout, i, mf);
    break;
  }
}

// ---------------------------------------------------------------------------
__device__ __forceinline__ void softmax256_wave(float* a, int lane){
  float v0=a[lane], v1=a[64+lane], v2=a[128+lane], v3=a[192+lane];
  float mx = fmaxf(fmaxf(v0,v1), fmaxf(v2,v3));
  #pragma unroll
  for (int off=32; off; off>>=1) mx = fmaxf(mx, __shfl_xor(mx, off, 64));
  v0=__expf(v0-mx); v1=__expf(v1-mx); v2=__expf(v2-mx); v3=__expf(v3-mx);
  float s = v0+v1+v2+v3;
  #pragma unroll
  for (int off=32; off; off>>=1) s += __shfl_xor(s, off, 64);
  float inv = frcp(s);
  a[lane]=v0*inv; a[64+lane]=v1*inv; a[128+lane]=v2*inv; a[192+lane]=v3*inv;
}

// ---- LDS overlays -------------------------------------------------------
struct ProdShm {
  bf16_t wpool[66560];     // 133 KB weight pool
  float  cst[64][16];
  float  bias[4][16];
};
// Consumer LDS. The union 'u' holds per-step-dead scratch (every member is
// fully rewritten each step before it is read) aliased with the link
// transpose-staging buffer tls (used only in R9b, after all scratch reads).
struct ConsShm {
  float smem[256][65];
  float wkn[64], ev_[64], wvv[64];
  float rs_[4], fg_[4], rm_[4][3];
  float wsS, agS, wgS, wwsumS;
  float invn[256];
  float usage[256];
  float ww_[256], prec_[256];
  float rw_[4][256];
  float rw4[256][4];
  float fwd_[4][256], bwd_[4][256], rcw_[4][256];
  bf16_t rwb[4][264];
  union {
    struct {
      float xib[480];
      float rkn4r[2][65][4];
      float wcw[256];
      float uu[256], su[256], scanA[256];
      int   rank_[256];
      float p2cT[2][264];
      float p5cT[5][2][264];
      float rvp[8][4][64];
    } a;
    bf16_t tls[32][258];   // 32 link rows x 256 cols (+2 pad: bank spread)
  } u;
};
union ShUnion { ProdShm p; ConsShm c; };

// ---------------------------------------------------------------------------
// Fused producer/consumer kernel.  128 blocks x 512 threads.
__global__ __launch_bounds__(512) void k_main(
    const bf16_t* __restrict__ xb, const bf16_t* __restrict__ h0b,
    const bf16_t* __restrict__ W0, const bf16_t* __restrict__ W1,
    const bf16_t* __restrict__ W2, const bf16_t* __restrict__ W3,
    const float* __restrict__ bs0, const float* __restrict__ bs1,
    const bf16_t* __restrict__ Wifp, const float* __restrict__ bifp,
    bf16_t* __restrict__ h0buf, bf16_t* __restrict__ h1buf,
    bf16_t* __restrict__ h0seq, bf16_t* __restrict__ outseq,
    float* __restrict__ XI, float* __restrict__ RVEC,
    unsigned* __restrict__ flg)
{
  __shared__ ShUnion sh;
  const int bid = blockIdx.x;
  const int tid = threadIdx.x, lane = tid & 63, wv = tid >> 6;
  const int m16 = lane & 15, q = lane >> 4;

  if (bid < 64){
    // ===================== PRODUCER: LSTM + xi tiles ======================
    ProdShm& P = sh.p;
    const int layer = bid >> 5;
    const int u0 = (bid & 31) * 16;

    if (!layer){
      for (int i = tid; i < 64*32; i += 512){
        int rl = i >> 5, c8 = (i & 31)*8;
        int grow = (rl >> 4)*512 + u0 + (rl & 15);
        *(bf16x8*)&P.wpool[rl*264 + c8] = *(const bf16x8*)(W0 + (size_t)grow*512 + c8);
      }
      for (int i = tid; i < 64*64; i += 512){
        int rl = i >> 6, c8 = (i & 63)*8;
        int grow = (rl >> 4)*512 + u0 + (rl & 15);
        *(bf16x8*)&P.wpool[16896 + rl*520 + c8] = *(const bf16x8*)(W1 + (size_t)grow*512 + c8);
      }
    } else {
      for (int i = tid; i < 64*64; i += 512){
        int rl = i >> 6, c8 = (i & 63)*8;
        int grow = (rl >> 4)*512 + u0 + (rl & 15);
        *(bf16x8*)&P.wpool[rl*520 + c8]         = *(const bf16x8*)(W2 + (size_t)grow*512 + c8);
        *(bf16x8*)&P.wpool[33280 + rl*520 + c8] = *(const bf16x8*)(W3 + (size_t)grow*512 + c8);
      }
    }
    for (int i = tid; i < 64*16; i += 512){
      int b = i >> 4, n = i & 15;
      P.cst[b][n] = (float)h0b[layer*(64*512) + b*512 + u0 + n];
    }
    if (tid < 64){
      int G = tid >> 4, n = tid & 15;
      const float* bs = layer ? bs1 : bs0;
      P.bias[G][n] = bs[G*512 + u0 + n];
    }
    __syncthreads();

    bf16_t* hbuf = layer ? h1buf : h0buf;

    for (int ps = 0; ps <= 33; ++ps){
      if (wv < 4){
        const int t = layer ? (ps - 1) : ps;
        const bool active = layer ? (ps >= 1 && ps <= 32) : (ps < 32);
        if (active){
          const int p = t & 1;
          const bf16_t* hin = hbuf + p*(64*512);
          bf16_t* hout = hbuf + (p^1)*(64*512);
          const int b0 = wv * 16;

          f32x4 acc[4];
          #pragma unroll
          for (int G = 0; G < 4; ++G){ float bv = P.bias[G][m16]; acc[G] = (f32x4){bv,bv,bv,bv}; }

          if (!layer){
            #pragma unroll 2
            for (int kt = 0; kt < 8; ++kt){
              bf16x8 a = *(const bf16x8*)(xb + ((size_t)(b0+m16)*T_ + t)*IN_ + kt*32 + q*8);
              #pragma unroll
              for (int G = 0; G < 4; ++G)
                acc[G] = __builtin_amdgcn_mfma_f32_16x16x32_bf16(
                    a, *(const bf16x8*)&P.wpool[(G*16+m16)*264 + kt*32 + q*8], acc[G], 0, 0, 0);
            }
            #pragma unroll 4
            for (int kt = 0; kt < 16; ++kt){
              bf16x8 a = *(const bf16x8*)(hin + (b0+m16)*512 + kt*32 + q*8);
              #pragma unroll
              for (int G = 0; G < 4; ++G)
                acc[G] = __builtin_amdgcn_mfma_f32_16x16x32_bf16(
                    a, *(const bf16x8*)&P.wpool[16896 + (G*16+m16)*520 + kt*32 + q*8], acc[G], 0, 0, 0);
            }
          } else {
            #pragma unroll 4
            for (int kt = 0; kt < 16; ++kt){
              bf16x8 a = *(const bf16x8*)(h0seq + ((size_t)t*64 + b0+m16)*512 + kt*32 + q*8);
              #pragma unroll
              for (int G = 0; G < 4; ++G)
                acc[G] = __builtin_amdgcn_mfma_f32_16x16x32_bf16(
                    a, *(const bf16x8*)&P.wpool[(G*16+m16)*520 + kt*32 + q*8], acc[G], 0, 0, 0);
            }
            #pragma unroll 4
            for (int kt = 0; kt < 16; ++kt){
              bf16x8 a = *(const bf16x8*)(hin + (b0+m16)*512 + kt*32 + q*8);
              #pragma unroll
              for (int G = 0; G < 4; ++G)
                acc[G] = __builtin_amdgcn_mfma_f32_16x16x32_bf16(
                    a, *(const bf16x8*)&P.wpool[33280 + (G*16+m16)*520 + kt*32 + q*8], acc[G], 0, 0, 0);
            }
          }
          #pragma unroll
          for (int v = 0; v < 4; ++v){
            int b = b0 + q*4 + v;
            float gi = acc[0][v], gf = acc[1][v], gg = acc[2][v], go = acc[3][v];
            float c_ = sigf(gf)*P.cst[b][m16] + sigf(gi)*tanh_f(gg);
            P.cst[b][m16] = c_;
            float h = sigf(go)*tanh_f(c_);
            bf16_t hb = (bf16_t)h;
            hout[b*512 + u0 + m16] = hb;
            if (!layer) h0seq[((size_t)t*64 + b)*512 + u0 + m16] = hb;
            else        outseq[((size_t)t*64 + b)*512 + u0 + m16] = hb;
          }
        }
      } else if (ps >= 2 && bid < 30){
        // xi tile for t2 = ps-2: rows bid*16..+16, batch-tile per wave
        const int t2 = ps - 2;
        const int b0 = (wv - 4) * 16;
        const int r = bid*16 + m16;          // < 480 (rows 471..479 zero-padded)
        float bv = bifp[r];
        f32x4 acc = {bv,bv,bv,bv};
        const bf16_t* arow = outseq + ((size_t)t2*64 + b0 + m16)*512 + q*8;
        const bf16_t* brow = Wifp + (size_t)r*512 + q*8;
        #pragma unroll 4
        for (int kt = 0; kt < 16; ++kt){
          acc = __builtin_amdgcn_mfma_f32_16x16x32_bf16(
              *(const bf16x8*)(arow + kt*32), *(const bf16x8*)(brow + kt*32), acc, 0, 0, 0);
        }
        #pragma unroll
        for (int v = 0; v < 4; ++v)
          XI[((size_t)t2*64 + b0 + q*4 + v)*480 + r] = acc[v];
      }
      flagbar(flg, bid, (unsigned)(ps + 1), tid, lane, wv);
    }
  } else {
    // ===================== CONSUMER: memory recurrence ====================
    ConsShm& S = sh.c;
    const int b = bid - 64;
    const int quad = lane >> 4, li = lane & 15;

    // ONE link copy (row-major): thread owns rows o_g = wv*32+g*16+li,
    // cols ch*32 + quad*8 .. +8 for ch = 0..7.  64 VGPRs total.
    bf16x8 rowL[2][8];
    #pragma unroll
    for (int g = 0; g < 2; ++g)
      #pragma unroll
      for (int ch = 0; ch < 8; ++ch)
        #pragma unroll
        for (int z = 0; z < 8; ++z) rowL[g][ch][z] = (bf16_t)0.0f;

    if (tid < 256){
      S.ww_[tid] = DELTA_; S.usage[tid] = 0.0f; S.prec_[tid] = 0.0f;
      S.invn[tid] = 1.0f/(fsqrt_(64.0f*DELTA_*DELTA_) + DELTA_);
      #pragma unroll
      for (int r = 0; r < 4; ++r) S.rw_[r][tid] = DELTA_;
    }
    for (int i = tid; i < 4*264; i += 512) ((bf16_t*)S.rwb)[i] = (bf16_t)DELTA_;
    for (int i = tid; i < 256*65; i += 512) ((float*)S.smem)[i] = DELTA_;
    __syncthreads();

    const int mH = tid >> 1, q2 = tid & 1;

    for (int t = 0; t < 32; ++t){
      // ---- R1: wait for XI[t] (all producer flags >= t+3), then load ----
      { const unsigned tgt = (unsigned)(t + 3);
        if (wv == 0){
          for (;;){
            unsigned f = flag_ld(flg + (size_t)lane*16);
            if (__all(f >= tgt)) break;
            __builtin_amdgcn_s_sleep(2);
          }
          __builtin_amdgcn_fence(__ATOMIC_ACQUIRE, "agent");
        }
        __syncthreads();
      }
      if (tid < IFACE_) S.u.a.xib[tid] = XI[((size_t)t*64 + b)*480 + tid];
      __syncthreads();

      // ---- R2: parse interface vector ----
      if (wv < 4){
        float v = tanh_f(S.u.a.xib[wv*64 + lane]);
        float s = wred(v*v);
        float vn = v * frcp(fsqrt_(s) + DELTA_);
        S.u.a.rkn4r[0][lane][wv] = vn; S.u.a.rkn4r[1][lane][wv] = vn;
      } else if (wv == 4){
        float v = tanh_f(S.u.a.xib[260 + lane]);
        float s = wred(v*v);
        S.wkn[lane] = v * frcp(fsqrt_(s) + DELTA_);
      } else if (wv == 5){ S.ev_[lane] = sigf(S.u.a.xib[325 + lane]);
      } else if (wv == 6){ S.wvv[lane] = tanh_f(S.u.a.xib[389 + lane]);
      } else {
        if (lane < 4)        S.rs_[lane] = softplusf(S.u.a.xib[256 + lane]);
        else if (lane == 4)  S.wsS = softplusf(S.u.a.xib[324]);
        else if (lane < 9)   S.fg_[lane-5] = sigf(S.u.a.xib[453 + (lane-5)]);
        else if (lane == 9)  S.agS = sigf(S.u.a.xib[457]);
        else if (lane == 10) S.wgS = sigf(S.u.a.xib[458]);
        else if (lane >= 16 && lane < 20){
          int r = lane - 16;
          float a0 = S.u.a.xib[459+r*3], a1 = S.u.a.xib[459+r*3+1], a2 = S.u.a.xib[459+r*3+2];
          float mx = fmaxf(a0, fmaxf(a1, a2));
          float e0 = __expf(a0-mx), e1 = __expf(a1-mx), e2 = __expf(a2-mx);
          float inv = frcp(e0+e1+e2);
          S.rm_[r][0]=e0*inv; S.rm_[r][1]=e1*inv; S.rm_[r][2]=e2*inv;
        }
      }
      __syncthreads();

      // ---- R3: usage update (tid<256) + write-content partials (all) ----
      if (tid < 256){
        int m = tid;
        float us = S.usage[m] + (1.0f - S.usage[m])*S.ww_[m];
        float psi = (1.0f - S.fg_[0]*S.rw_[0][m]) * (1.0f - S.fg_[1]*S.rw_[1][m])
                  * (1.0f - S.fg_[2]*S.rw_[2][m]) * (1.0f - S.fg_[3]*S.rw_[3][m]);
        us *= psi;
        S.usage[m] = us;
        S.u.a.uu[m] = DELTA_ + (1.0f - DELTA_)*us;
      }
      { float acc = 0.0f;
        #pragma unroll
        for (int it = 0; it < 32; ++it){
          int w = q2*32 + it;
          acc += S.smem[mH][w] * S.wkn[w];
        }
        S.u.a.p2cT[q2][mH] = acc; }
      __syncthreads();

      // ---- R4: wave0: wcw combine + softmax ; waves 4-7: rank-sort ----
      if (wv == 0){
        #pragma unroll
        for (int z = 0; z < 4; ++z){
          int m = z*64 + lane;
          S.u.a.wcw[m] = S.wsS * (S.u.a.p2cT[0][m] + S.u.a.p2cT[1][m]) * S.invn[m];
        }
        softmax256_wave(S.u.a.wcw, lane);
      } else if (tid >= 256){
        const int i = tid - 256;
        const float ui = S.u.a.uu[i];
        int cnt = 0;
        #pragma unroll 8
        for (int k = 0; k < 64; ++k){
          f32x4 u4 = *(const f32x4*)&S.u.a.uu[k*4];
          #pragma unroll
          for (int z = 0; z < 4; ++z){
            int j = k*4 + z; float uj = u4[z];
            cnt += (uj < ui || (uj == ui && j < i)) ? 1 : 0;
          }
        }
        S.u.a.rank_[i] = cnt;
        S.u.a.su[cnt] = ui;
      }
      __syncthreads();

      // ---- R5: exclusive product scan of su -> scanA (wave 0) ----
      if (wv == 0){
        int base = lane*4;
        float v0 = S.u.a.su[base], v1 = S.u.a.su[base+1], v2 = S.u.a.su[base+2];
        float p1 = v0*v1, p2 = p1*v2, p3 = p2*S.u.a.su[base+3];
        float sc = p3;
        #pragma unroll
        for (int off = 1; off < 64; off <<= 1){
          float n = __shfl_up(sc, off, 64);
          if (lane >= off) sc *= n;
        }
        float exch = __shfl_up(sc, 1, 64);
        if (lane == 0) exch = 1.0f;
        S.u.a.scanA[base] = exch; S.u.a.scanA[base+1] = exch*v0;
        S.u.a.scanA[base+2] = exch*p1; S.u.a.scanA[base+3] = exch*p2;
      }
      __syncthreads();

      // ---- R7: ww + mem erase/write (smem-resident) + partials ----
      { const int m = mH;
        float al = (1.0f - S.u.a.uu[m]) * S.u.a.scanA[S.u.a.rank_[m]];
        float wm = S.wgS*(S.agS*al + (1.0f - S.agS)*S.u.a.wcw[m]);
        if (q2 == 0) S.ww_[m] = wm;
        float s2 = 0.0f, sr0 = 0.0f, sr1 = 0.0f, sr2 = 0.0f, sr3 = 0.0f;
        #pragma unroll
        for (int it = 0; it < 32; ++it){
          int w = q2*32 + it;
          float mn = S.smem[m][w]*(1.0f - wm*S.ev_[w]) + wm*S.wvv[w];
          S.smem[m][w] = mn;
          s2 += mn*mn;
          f32x4 rk = *(const f32x4*)&S.u.a.rkn4r[q2][w][0];
          sr0 += mn*rk[0]; sr1 += mn*rk[1]; sr2 += mn*rk[2]; sr3 += mn*rk[3];
        }
        S.u.a.p5cT[0][q2][m] = s2;
        S.u.a.p5cT[1][q2][m] = sr0; S.u.a.p5cT[2][q2][m] = sr1;
        S.u.a.p5cT[3][q2][m] = sr2; S.u.a.p5cT[4][q2][m] = sr3; }
      __syncthreads();

      // ---- R8: norm + read-content pre-softmax (tid<256); wave4: wwsum ----
      if (tid < 256){
        int m = tid;
        float s2 = S.u.a.p5cT[0][0][m] + S.u.a.p5cT[0][1][m];
        float inv = frcp(fsqrt_(s2) + DELTA_);
        S.invn[m] = inv;
        #pragma unroll
        for (int r = 0; r < 4; ++r){
          float sr = S.u.a.p5cT[r+1][0][m] + S.u.a.p5cT[r+1][1][m];
          S.rcw_[r][m] = S.rs_[r]*sr*inv;
        }
      } else if (wv == 4){
        float s = wred(S.ww_[lane] + S.ww_[64+lane] + S.ww_[128+lane] + S.ww_[192+lane]);
        if (lane == 0) S.wwsumS = s;
      }
      __syncthreads();

      // ---- R9a: link row update + fwd via MFMA ----
      f32x4 bacc[2] = {{0,0,0,0},{0,0,0,0}};
      { float wown[2], pown[2], alpha[2];
        #pragma unroll
        for (int g = 0; g < 2; ++g){
          int o = wv*32 + g*16 + li;
          wown[g] = S.ww_[o]; pown[g] = S.prec_[o];
          alpha[g] = 1.0f - wown[g];
        }
        f32x4 facc[2] = {{0,0,0,0},{0,0,0,0}};
        #pragma unroll
        for (int ch = 0; ch < 8; ++ch){
          const int cbase = ch*32 + quad*8;
          bf16x8 rwf = *(const bf16x8*)&S.rwb[li & 3][cbase];
          f32x4 wA = *(const f32x4*)&S.ww_[cbase];
          f32x4 wB = *(const f32x4*)&S.ww_[cbase+4];
          f32x4 pA = *(const f32x4*)&S.prec_[cbase];
          f32x4 pB = *(const f32x4*)&S.prec_[cbase+4];
          float wcf[8] = {wA[0],wA[1],wA[2],wA[3],wB[0],wB[1],wB[2],wB[3]};
          float pcf[8] = {pA[0],pA[1],pA[2],pA[3],pB[0],pB[1],pB[2],pB[3]};
          #pragma unroll
          for (int g = 0; g < 2; ++g){
            const int o = wv*32 + g*16 + li;
            bf16x8 rl = rowL[g][ch];
            #pragma unroll
            for (int jj = 0; jj < 8; ++jj){
              const int c = cbase + jj;
              float s = alpha[g] - wcf[jj];
              float vr = s*(float)rl[jj] + wown[g]*pcf[jj];
              if (c == o) vr = 0.0f;
              rl[jj] = (bf16_t)vr;
            }
            rowL[g][ch] = rl;
            facc[g] = __builtin_amdgcn_mfma_f32_16x16x32_bf16(rl, rwf, facc[g], 0, 0, 0);
          }
        }
        #pragma unroll
        for (int g = 0; g < 2; ++g)
          if (li < 4){
            #pragma unroll
            for (int z = 0; z < 4; ++z) S.fwd_[li][wv*32 + g*16 + quad*4 + z] = facc[g][z];
          }
      }
      __syncthreads();   // R8 scratch reads done; tls staging may begin

      // ---- R9b: bwd via 8 sub-phases of LDS transpose staging ----
      #pragma unroll 1
      for (int sub = 0; sub < 8; ++sub){
        if (wv == sub){
          #pragma unroll
          for (int g = 0; g < 2; ++g)
            #pragma unroll
            for (int ch = 0; ch < 8; ++ch)
              *(bf16x8*)&S.u.tls[g*16 + li][ch*32 + quad*8] = rowL[g][ch];
        }
        __syncthreads();
        { const int cb = sub*32 + quad*8;
          bf16x8 rwf = *(const bf16x8*)&S.rwb[li & 3][cb];
          #pragma unroll
          for (int g = 0; g < 2; ++g){
            const int x = wv*32 + g*16 + li;
            bf16x8 cl;
            #pragma unroll
            for (int z = 0; z < 8; ++z) cl[z] = S.u.tls[quad*8 + z][x];
            bacc[g] = __builtin_amdgcn_mfma_f32_16x16x32_bf16(rwf, cl, bacc[g], 0, 0, 0);
          }
        }
        __syncthreads();
      }
      #pragma unroll
      for (int g = 0; g < 2; ++g)
        if (quad == 0){
          #pragma unroll
          for (int z = 0; z < 4; ++z) S.bwd_[z][wv*32 + g*16 + li] = bacc[g][z];
        }
      __syncthreads();

      // ---- R10: waves0-3: rcw softmax ; waves4-7: precedence ----
      if (wv < 4) softmax256_wave(S.rcw_[wv], lane);
      else {
        int m = tid - 256;
        float p = (1.0f - S.wwsumS)*S.prec_[m] + S.ww_[m];
        S.prec_[m] = p;
      }
      __syncthreads();

      // ---- R11: new read weights ----
      { int r = tid >> 7, m0 = (tid & 127)*2;
        #pragma unroll
        for (int z = 0; z < 2; ++z){
          int m = m0 + z;
          float v = S.rm_[r][0]*S.bwd_[r][m] + S.rm_[r][1]*S.fwd_[r][m] + S.rm_[r][2]*S.rcw_[r][m];
          S.rw_[r][m] = v;
          S.rw4[m][r] = v;
          S.rwb[r][m] = (bf16_t)v;
        } }
      __syncthreads();

      // ---- R12: read vectors: wave-per-32-rows ----
      { float r0 = 0, r1 = 0, r2 = 0, r3 = 0;
        #pragma unroll
        for (int k = 0; k < 32; ++k){
          int m = wv*32 + k;
          f32x4 r4 = *(const f32x4*)&S.rw4[m][0];
          float mv = S.smem[m][lane];
          r0 += r4[0]*mv; r1 += r4[1]*mv; r2 += r4[2]*mv; r3 += r4[3]*mv;
        }
        S.u.a.rvp[wv][0][lane] = r0; S.u.a.rvp[wv][1][lane] = r1;
        S.u.a.rvp[wv][2][lane] = r2; S.u.a.rvp[wv][3][lane] = r3; }
      __syncthreads();

      // ---- R13: combine + store ----
      if (tid < 256){
        const int w = tid & 63, r = tid >> 6;
        float v = 0.0f;
        #pragma unroll
        for (int c = 0; c < 8; ++c) v += S.u.a.rvp[c][r][w];
        RVEC[((size_t)t*64 + b)*256 + tid] = v;
      }
      __syncthreads();
    }
  }
}

// ---------------------------------------------------------------------------
__global__ void k_tanhy(const bf16_t* __restrict__ outseq, const float* __restrict__ RVEC,
                        bf16_t* __restrict__ Y){
  const int n = 2048*768;
  for (int i = blockIdx.x*blockDim.x + threadIdx.x; i < n; i += gridDim.x*blockDim.x){
    int row = i / 768, j = i - row*768;
    float v = (j < 512) ? (float)outseq[(size_t)row*512 + j] : RVEC[(size_t)row*256 + (j - 512)];
    Y[i] = (bf16_t)tanh_f(v);
  }
}

__global__ __launch_bounds__(256,1) void k_out(
    const bf16_t* __restrict__ Y, const bf16_t* __restrict__ Woutb,
    const float* __restrict__ boutf, void* __restrict__ dout,
    const int* __restrict__ flag)
{
  const int mf = *flag;
  const int mt = blockIdx.x;          // 0..127
  const int tid = threadIdx.x, lane = tid & 63, wv = tid >> 6;
  const int nt = blockIdx.y*4 + wv;   // 0..15
  const int m16 = lane & 15, q = lane >> 4;
  const int o = nt*16 + m16;
  float bv = boutf[o];
  f32x4 acc = {bv,bv,bv,bv};
  const bf16_t* arow = Y + (size_t)(mt*16 + m16)*768 + q*8;
  const bf16_t* brow = Woutb + (size_t)o*768 + q*8;
  for (int kt = 0; kt < 24; ++kt){
    acc = __builtin_amdgcn_mfma_f32_16x16x32_bf16(
        *(const bf16x8*)(arow + kt*32), *(const bf16x8*)(brow + kt*32), acc, 0, 0, 0);
  }
  #pragma unroll
  for (int v = 0; v < 4; ++v){
    int row = mt*16 + q*4 + v;        // = t*64 + b
    int b = row & 63, t = row >> 6;
    size_t idx = ((size_t)b*T_ + t)*256 + o;
    if (mf) ((float*)dout)[idx] = acc[v];
    else    ((bf16_t*)dout)[idx] = (bf16_t)acc[v];
  }
}

// ---------------------------------------------------------------------------
extern "C" void kernel_launch(void* const* d_in, const int* in_sizes, int n_in,
                              void* d_out, int out_size, void* d_ws, size_t ws_size,
                              hipStream_t stream)
{
  char* ws = (char*)d_ws;
  bf16_t* H0SEQ  = (bf16_t*)(ws + OFF_H0SEQ);
  bf16_t* OUTSEQ = (bf16_t*)(ws + OFF_OUTSEQ);
  bf16_t* H0BUF  = (bf16_t*)(ws + OFF_H0BUF);
  bf16_t* H1BUF  = (bf16_t*)(ws + OFF_H1BUF);
  float*  XI     = (float*) (ws + OFF_XI);
  float*  RVEC   = (float*) (ws + OFF_RVEC);
  bf16_t* YBF    = (bf16_t*)(ws + OFF_YBF);
  unsigned* BAR  = (unsigned*)(ws + OFF_BAR);
  int*    FLAG   = (int*)   (ws + OFF_BAR + 8);
  bf16_t* XB     = (bf16_t*)(ws + OFF_XB);
  bf16_t* H0B    = (bf16_t*)(ws + OFF_H0B);
  bf16_t* W0     = (bf16_t*)(ws + OFF_W0);
  bf16_t* W1     = (bf16_t*)(ws + OFF_W1);
  bf16_t* W2     = (bf16_t*)(ws + OFF_W2);
  bf16_t* W3     = (bf16_t*)(ws + OFF_W3);
  bf16_t* WIFP   = (bf16_t*)(ws + OFF_WIF);
  bf16_t* WOUTB  = (bf16_t*)(ws + OFF_WOUTB);
  float*  BS0    = (float*) (ws + OFF_BS0);
  float*  BS1    = (float*) (ws + OFF_BS1);
  float*  BIFP   = (float*) (ws + OFF_BIF);
  float*  BOUTF  = (float*) (ws + OFF_BOUTF);
  unsigned* FLG  = (unsigned*)(ws + OFF_FLG);

  k_detect<<<1, 256, 0, stream>>>((const unsigned short*)d_in[0], FLAG, BAR, FLG);
  k_convert<<<dim3(256, 9), 256, 0, stream>>>(
      d_in[0], d_in[1], d_in[2], d_in[3], d_in[4], d_in[5], d_in[6],
      d_in[7], d_in[8], d_in[9], d_in[10], d_in[11], d_in[12], d_in[13],
      XB, H0B, H0BUF, H1BUF, W0, W1, W2, W3, WIFP, WOUTB,
      BS0, BS1, BIFP, BOUTF, FLAG);
  k_main<<<128, 512, 0, stream>>>(XB, H0B, W0, W1, W2, W3, BS0, BS1,
                                  WIFP, BIFP, H0BUF, H1BUF, H0SEQ, OUTSEQ,
                                  XI, RVEC, FLG);
  k_tanhy<<<512, 256, 0, stream>>>(OUTSEQ, RVEC, YBF);
  k_out<<<dim3(128, 4), 256, 0, stream>>>(YBF, WOUTB, BOUTF, d_out, FLAG);
}

// Round 12
// 969.751 us; speedup vs baseline: 1.1449x; 1.1449x over previous
//
#include <hip/hip_runtime.h>
#include <hip/hip_bf16.h>
#include <math.h>

// ---------------------------------------------------------------------------
// DNC forward on MI355X — 16-wave consumer, 64-VGPR-fitting state.
//   k_main: 128 blocks x 1024 threads (16 waves).
//     blocks 0-63  (producers): LSTM waves 0-3, xi waves 4-7; 34 phases.
//     blocks 64-127 (consumers): DNC memory recurrence, 1 block/batch.
//       Design point from r7/r11 evidence: 16 waves (919us) beat 8 (956-1010)
//       even with 48MB scratch spills; 512-thr spills were mild (~3MB).
//       => keep 16 waves, shrink state to the 64-VGPR budget:
//       - ONE link copy (rowL[8] = 32 VGPR; colL dropped)
//       - mem rows smem-resident (mr dropped)
//       - bwd = L^T rw via 8 tls sub-phases (2 waves co-write 32 rows into a
//         16.5KB LDS buffer union-aliased over per-step-dead scratch)
//   k_tanhy / k_out unchanged.
// ---------------------------------------------------------------------------

typedef __bf16 bf16_t;
typedef __attribute__((ext_vector_type(8))) __bf16 bf16x8;
typedef __attribute__((ext_vector_type(4))) float f32x4;

#define B_    64
#define T_    32
#define IN_   256
#define H_    512
#define M_    256
#define W_    64
#define R_    4
#define IFACE_ 471
#define DELTA_ 1e-6f

// ---------------- ws layout (bytes) ----------------
#define OFF_H0SEQ  (0L)
#define SZ_H0SEQ   (32L*64*512*2)
#define OFF_OUTSEQ (OFF_H0SEQ + SZ_H0SEQ)
#define SZ_OUTSEQ  (32L*64*512*2)
#define OFF_H0BUF  (OFF_OUTSEQ + SZ_OUTSEQ)
#define SZ_HBUF    (2L*64*512*2)
#define OFF_H1BUF  (OFF_H0BUF + SZ_HBUF)
#define OFF_XI     (OFF_H1BUF + SZ_HBUF)
#define SZ_XI      (32L*64*480*4)
#define OFF_RVEC   (OFF_XI + SZ_XI)
#define SZ_RVEC    (32L*64*256*4)
#define OFF_YBF    (OFF_RVEC + SZ_RVEC)
#define SZ_YBF     (32L*64*768*2)
#define OFF_BAR    (OFF_YBF + SZ_YBF)
#define SZ_BAR     (256L)
#define OFF_XB     (OFF_BAR + SZ_BAR)
#define SZ_XB      (64L*32*256*2)
#define OFF_H0B    (OFF_XB + SZ_XB)
#define SZ_H0B     (2L*64*512*2)
#define OFF_W0     (OFF_H0B + SZ_H0B)
#define SZ_W       (2048L*512*2)
#define OFF_W1     (OFF_W0 + SZ_W)
#define OFF_W2     (OFF_W1 + SZ_W)
#define OFF_W3     (OFF_W2 + SZ_W)
#define OFF_WIF    (OFF_W3 + SZ_W)
#define SZ_WIF     (480L*512*2)
#define OFF_WOUTB  (OFF_WIF + SZ_WIF)
#define SZ_WOUTB   (256L*768*2)
#define OFF_BS0    (OFF_WOUTB + SZ_WOUTB)
#define SZ_BS      (2048L*4)
#define OFF_BS1    (OFF_BS0 + SZ_BS)
#define OFF_BIF    (OFF_BS1 + SZ_BS)
#define SZ_BIF     (2048L)
#define OFF_BOUTF  (OFF_BIF + SZ_BIF)
#define SZ_BOUTF   (1024L)
#define OFF_FLG    (OFF_BOUTF + SZ_BOUTF)
#define SZ_FLG     (4096L)                // 64 per-block flags, 64B apart

// ---- fast native math ----
__device__ __forceinline__ float frcp(float x){ return __builtin_amdgcn_rcpf(x); }
__device__ __forceinline__ float fsqrt_(float x){ return __builtin_amdgcn_sqrtf(x); }
__device__ __forceinline__ float sigf(float x){ return frcp(1.0f + __expf(-x)); }
__device__ __forceinline__ float tanh_f(float x){
  float xc = fminf(fmaxf(x, -44.0f), 44.0f);
  float t = __expf(2.0f * xc);
  return (t - 1.0f) * frcp(t + 1.0f);
}
__device__ __forceinline__ float softplusf(float x){
  return fmaxf(x, 0.0f) + __logf(1.0f + __expf(-fabsf(x)));
}
__device__ __forceinline__ float wred(float v){
  #pragma unroll
  for (int off = 32; off; off >>= 1) v += __shfl_xor(v, off, 64);
  return v;
}
__device__ __forceinline__ float ldin(const void* p, long i, int mf){
  return mf ? ((const float*)p)[i] : (float)((const bf16_t*)p)[i];
}

__device__ __forceinline__ unsigned flag_ld(const unsigned* p){
  return __hip_atomic_load(p, __ATOMIC_RELAXED, __HIP_MEMORY_SCOPE_AGENT);
}

// producer phase barrier: release store + wave-0 relaxed poll + acquire fence.
__device__ __forceinline__ void flagbar(unsigned* flg, int bid, unsigned tgt,
                                        int tid, int lane, int wv){
  __syncthreads();
  if (tid == 0)
    __hip_atomic_store(flg + (size_t)bid*16, tgt, __ATOMIC_RELEASE,
                       __HIP_MEMORY_SCOPE_AGENT);
  if (wv == 0){
    for (;;){
      unsigned f = flag_ld(flg + (size_t)lane*16);
      if (__all(f >= tgt)) break;
      __builtin_amdgcn_s_sleep(2);
    }
    __builtin_amdgcn_fence(__ATOMIC_ACQUIRE, "agent");
  }
  __syncthreads();
}

// ---------------------------------------------------------------------------
__global__ void k_detect(const unsigned short* __restrict__ x16,
                         int* __restrict__ flag, unsigned* __restrict__ bar,
                         unsigned* __restrict__ flg){
  __shared__ int cnt;
  if (threadIdx.x == 0){ cnt = 0; bar[0] = 0u; bar[1] = 0u; }
  for (int i = threadIdx.x; i < 1024; i += 256) flg[i] = 0u;
  __syncthreads();
  unsigned short u = x16[threadIdx.x * 2];
  int e = (u >> 7) & 0xFF;
  if (e >= 0x88) atomicAdd(&cnt, 1);
  __syncthreads();
  if (threadIdx.x == 0) *flag = (cnt > 16) ? 1 : 0;
}

// ---------------------------------------------------------------------------
__global__ void k_convert(const void* x, const void* h0, const void* Wih0,
                          const void* Whh0, const void* bih0, const void* bhh0,
                          const void* Wih1, const void* Whh1, const void* bih1,
                          const void* bhh1, const void* Wif, const void* bif,
                          const void* Wout, const void* bout,
                          bf16_t* __restrict__ xb, bf16_t* __restrict__ h0b,
                          bf16_t* __restrict__ h0buf, bf16_t* __restrict__ h1buf,
                          bf16_t* __restrict__ W0, bf16_t* __restrict__ W1,
                          bf16_t* __restrict__ W2, bf16_t* __restrict__ W3,
                          bf16_t* __restrict__ Wifp, bf16_t* __restrict__ Woutb,
                          float* __restrict__ bs0, float* __restrict__ bs1,
                          float* __restrict__ bifp, float* __restrict__ boutf,
                          const int* __restrict__ flag)
{
  const int mf = *flag;
  const long stride = (long)gridDim.x * blockDim.x;
  long i0 = (long)blockIdx.x * blockDim.x + threadIdx.x;
  switch (blockIdx.y){
  case 0: for (long i = i0; i < 64L*32*256; i += stride) xb[i] = (bf16_t)ldin(x, i, mf); break;
  case 1: for (long i = i0; i < 2L*64*512; i += stride){
            float v = ldin(h0, i, mf); bf16_t bb = (bf16_t)v; h0b[i] = bb;
            if (i < 64*512) h0buf[i] = bb; else h1buf[i - 64*512] = bb;
          } break;
  case 2: for (long i = i0; i < 2048L*512; i += stride) W0[i] = (bf16_t)ldin(Wih0, i, mf); break;
  case 3: for (long i = i0; i < 2048L*512; i += stride) W1[i] = (bf16_t)ldin(Whh0, i, mf); break;
  case 4: for (long i = i0; i < 2048L*512; i += stride) W2[i] = (bf16_t)ldin(Wih1, i, mf); break;
  case 5: for (long i = i0; i < 2048L*512; i += stride) W3[i] = (bf16_t)ldin(Whh1, i, mf); break;
  case 6: for (long i = i0; i < 480L*512; i += stride){
            long r = i >> 9;
            Wifp[i] = (r < IFACE_) ? (bf16_t)ldin(Wif, i, mf) : (bf16_t)0.0f;
          } break;
  case 7: for (long i = i0; i < 256L*768; i += stride) Woutb[i] = (bf16_t)ldin(Wout, i, mf); break;
  case 8:
    for (long i = i0; i < 2048; i += stride){
      bs0[i] = ldin(bih0, i, mf) + ldin(bhh0, i, mf);
      bs1[i] = ldin(bih1, i, mf) + ldin(bhh1, i, mf);
    }
    for (long i = i0; i < 480; i += stride) bifp[i] = (i < IFACE_) ? ldin(bif, i, mf) : 0.0f;
    for (long i = i0; i < 256; i += stride) boutf[i] = ldin(bout, i, mf);
    break;
  }
}

// ---------------------------------------------------------------------------
__device__ __forceinline__ void softmax256_wave(float* a, int lane){
  float v0=a[lane], v1=a[64+lane], v2=a[128+lane], v3=a[192+lane];
  float mx = fmaxf(fmaxf(v0,v1), fmaxf(v2,v3));
  #pragma unroll
  for (int off=32; off; off>>=1) mx = fmaxf(mx, __shfl_xor(mx, off, 64));
  v0=__expf(v0-mx); v1=__expf(v1-mx); v2=__expf(v2-mx); v3=__expf(v3-mx);
  float s = v0+v1+v2+v3;
  #pragma unroll
  for (int off=32; off; off>>=1) s += __shfl_xor(s, off, 64);
  float inv = frcp(s);
  a[lane]=v0*inv; a[64+lane]=v1*inv; a[128+lane]=v2*inv; a[192+lane]=v3*inv;
}

// ---- LDS overlays -------------------------------------------------------
struct ProdShm {
  bf16_t wpool[66560];     // 133 KB weight pool
  float  cst[64][16];
  float  bias[4][16];
};
// Consumer LDS. Union 'u': per-step-dead scratch (struct a; every member
// written+read within one step, all reads complete before R9b) aliased with
// the link transpose-staging buffer tls (written/read only in R9b).
struct ConsShm {
  float smem[256][65];
  float wkn[64], ev_[64], wvv[64];
  float rs_[4], fg_[4], rm_[4][3];
  float wsS, agS, wgS, wwsumS;
  float invn[256];
  float usage[256];
  float ww_[256], prec_[256];
  float rw_[4][256];
  float rw4[256][4];
  float fwd_[4][256], bwd_[4][256], rcw_[4][256];
  bf16_t rwb[4][264];
  union {
    struct {
      float rkn4r[4][65][4];     // R2 -> R7
      float wcw[256];            // R4 -> R7
      float uu[256];             // R3 -> R7
      float su[256];             // R4 -> R5b
      float scanA[256];          // R5b -> R7
      int   rank_[256];          // R5a -> R7
      int   rankP[2][256];       // R4 -> R5a
      float p4cT[4][264];        // R3 -> R4
      float p5cT[5][4][264];     // R7 -> R8
      float rvp[16][4][64];      // R12 -> R13 (after R9b)
    } a;
    bf16_t tls[32][258];         // R9b only: 32 link rows x 256 (+2 pad)
  } u;
};
union ShUnion { ProdShm p; ConsShm c; };

// ---------------------------------------------------------------------------
// Fused producer/consumer kernel.  128 blocks x 1024 threads.
__global__ __launch_bounds__(1024) void k_main(
    const bf16_t* __restrict__ xb, const bf16_t* __restrict__ h0b,
    const bf16_t* __restrict__ W0, const bf16_t* __restrict__ W1,
    const bf16_t* __restrict__ W2, const bf16_t* __restrict__ W3,
    const float* __restrict__ bs0, const float* __restrict__ bs1,
    const bf16_t* __restrict__ Wifp, const float* __restrict__ bifp,
    bf16_t* __restrict__ h0buf, bf16_t* __restrict__ h1buf,
    bf16_t* __restrict__ h0seq, bf16_t* __restrict__ outseq,
    float* __restrict__ XI, float* __restrict__ RVEC,
    unsigned* __restrict__ flg)
{
  __shared__ ShUnion sh;
  const int bid = blockIdx.x;
  const int tid = threadIdx.x, lane = tid & 63, wv = tid >> 6;
  const int m16 = lane & 15, q = lane >> 4;

  if (bid < 64){
    // ===================== PRODUCER: LSTM + xi tiles ======================
    ProdShm& P = sh.p;
    const int layer = bid >> 5;
    const int u0 = (bid & 31) * 16;

    if (!layer){
      for (int i = tid; i < 64*32; i += 1024){
        int rl = i >> 5, c8 = (i & 31)*8;
        int grow = (rl >> 4)*512 + u0 + (rl & 15);
        *(bf16x8*)&P.wpool[rl*264 + c8] = *(const bf16x8*)(W0 + (size_t)grow*512 + c8);
      }
      for (int i = tid; i < 64*64; i += 1024){
        int rl = i >> 6, c8 = (i & 63)*8;
        int grow = (rl >> 4)*512 + u0 + (rl & 15);
        *(bf16x8*)&P.wpool[16896 + rl*520 + c8] = *(const bf16x8*)(W1 + (size_t)grow*512 + c8);
      }
    } else {
      for (int i = tid; i < 64*64; i += 1024){
        int rl = i >> 6, c8 = (i & 63)*8;
        int grow = (rl >> 4)*512 + u0 + (rl & 15);
        *(bf16x8*)&P.wpool[rl*520 + c8]         = *(const bf16x8*)(W2 + (size_t)grow*512 + c8);
        *(bf16x8*)&P.wpool[33280 + rl*520 + c8] = *(const bf16x8*)(W3 + (size_t)grow*512 + c8);
      }
    }
    for (int i = tid; i < 64*16; i += 1024){
      int b = i >> 4, n = i & 15;
      P.cst[b][n] = (float)h0b[layer*(64*512) + b*512 + u0 + n];
    }
    if (tid < 64){
      int G = tid >> 4, n = tid & 15;
      const float* bs = layer ? bs1 : bs0;
      P.bias[G][n] = bs[G*512 + u0 + n];
    }
    __syncthreads();

    bf16_t* hbuf = layer ? h1buf : h0buf;

    for (int ps = 0; ps <= 33; ++ps){
      if (wv < 4){
        const int t = layer ? (ps - 1) : ps;
        const bool active = layer ? (ps >= 1 && ps <= 32) : (ps < 32);
        if (active){
          const int p = t & 1;
          const bf16_t* hin = hbuf + p*(64*512);
          bf16_t* hout = hbuf + (p^1)*(64*512);
          const int b0 = wv * 16;

          f32x4 acc[4];
          #pragma unroll
          for (int G = 0; G < 4; ++G){ float bv = P.bias[G][m16]; acc[G] = (f32x4){bv,bv,bv,bv}; }

          if (!layer){
            #pragma unroll 2
            for (int kt = 0; kt < 8; ++kt){
              bf16x8 a = *(const bf16x8*)(xb + ((size_t)(b0+m16)*T_ + t)*IN_ + kt*32 + q*8);
              #pragma unroll
              for (int G = 0; G < 4; ++G)
                acc[G] = __builtin_amdgcn_mfma_f32_16x16x32_bf16(
                    a, *(const bf16x8*)&P.wpool[(G*16+m16)*264 + kt*32 + q*8], acc[G], 0, 0, 0);
            }
            #pragma unroll 4
            for (int kt = 0; kt < 16; ++kt){
              bf16x8 a = *(const bf16x8*)(hin + (b0+m16)*512 + kt*32 + q*8);
              #pragma unroll
              for (int G = 0; G < 4; ++G)
                acc[G] = __builtin_amdgcn_mfma_f32_16x16x32_bf16(
                    a, *(const bf16x8*)&P.wpool[16896 + (G*16+m16)*520 + kt*32 + q*8], acc[G], 0, 0, 0);
            }
          } else {
            #pragma unroll 4
            for (int kt = 0; kt < 16; ++kt){
              bf16x8 a = *(const bf16x8*)(h0seq + ((size_t)t*64 + b0+m16)*512 + kt*32 + q*8);
              #pragma unroll
              for (int G = 0; G < 4; ++G)
                acc[G] = __builtin_amdgcn_mfma_f32_16x16x32_bf16(
                    a, *(const bf16x8*)&P.wpool[(G*16+m16)*520 + kt*32 + q*8], acc[G], 0, 0, 0);
            }
            #pragma unroll 4
            for (int kt = 0; kt < 16; ++kt){
              bf16x8 a = *(const bf16x8*)(hin + (b0+m16)*512 + kt*32 + q*8);
              #pragma unroll
              for (int G = 0; G < 4; ++G)
                acc[G] = __builtin_amdgcn_mfma_f32_16x16x32_bf16(
                    a, *(const bf16x8*)&P.wpool[33280 + (G*16+m16)*520 + kt*32 + q*8], acc[G], 0, 0, 0);
            }
          }
          #pragma unroll
          for (int v = 0; v < 4; ++v){
            int b = b0 + q*4 + v;
            float gi = acc[0][v], gf = acc[1][v], gg = acc[2][v], go = acc[3][v];
            float c_ = sigf(gf)*P.cst[b][m16] + sigf(gi)*tanh_f(gg);
            P.cst[b][m16] = c_;
            float h = sigf(go)*tanh_f(c_);
            bf16_t hb = (bf16_t)h;
            hout[b*512 + u0 + m16] = hb;
            if (!layer) h0seq[((size_t)t*64 + b)*512 + u0 + m16] = hb;
            else        outseq[((size_t)t*64 + b)*512 + u0 + m16] = hb;
          }
        }
      } else if (wv < 8 && ps >= 2 && bid < 30){
        // xi tile for t2 = ps-2: rows bid*16..+16, batch-tile per wave
        const int t2 = ps - 2;
        const int b0 = (wv - 4) * 16;
        const int r = bid*16 + m16;          // < 480 (rows 471..479 zero-padded)
        float bv = bifp[r];
        f32x4 acc = {bv,bv,bv,bv};
        const bf16_t* arow = outseq + ((size_t)t2*64 + b0 + m16)*512 + q*8;
        const bf16_t* brow = Wifp + (size_t)r*512 + q*8;
        #pragma unroll 4
        for (int kt = 0; kt < 16; ++kt){
          acc = __builtin_amdgcn_mfma_f32_16x16x32_bf16(
              *(const bf16x8*)(arow + kt*32), *(const bf16x8*)(brow + kt*32), acc, 0, 0, 0);
        }
        #pragma unroll
        for (int v = 0; v < 4; ++v)
          XI[((size_t)t2*64 + b0 + q*4 + v)*480 + r] = acc[v];
      }
      flagbar(flg, bid, (unsigned)(ps + 1), tid, lane, wv);
    }
  } else {
    // ===================== CONSUMER: memory recurrence ====================
    ConsShm& S = sh.c;
    const int b = bid - 64;
    const int quad = lane >> 4, li = lane & 15;

    // ONE link copy: thread owns row orow = wv*16+li, cols ch*32+quad*8..+8.
    const int orow = wv*16 + li;
    bf16x8 rowL[8];
    #pragma unroll
    for (int ch = 0; ch < 8; ++ch)
      #pragma unroll
      for (int z = 0; z < 8; ++z) rowL[ch][z] = (bf16_t)0.0f;

    // memory ownership (smem-resident): thread (mQ = tid>>2, q4 = tid&3)
    // owns mem[mQ][q4*16 .. q4*16+15]
    const int mQ = tid >> 2, q4 = tid & 3;

    // per-thread XI gather offsets (parse-from-registers; <=3 elements)
    int off0 = -1, off1 = -1, off2 = -1;
    if (wv < 4)            off0 = wv*64 + lane;
    else if (wv == 4)      off0 = 260 + lane;
    else if (wv == 5)      off0 = 325 + lane;
    else if (wv == 6)      off0 = 389 + lane;
    else if (wv == 7){
      if (lane < 4)        off0 = 256 + lane;
      else if (lane == 4)  off0 = 324;
      else if (lane < 9)   off0 = 453 + (lane - 5);
      else if (lane == 9)  off0 = 457;
      else if (lane == 10) off0 = 458;
      else if (lane >= 16 && lane < 20){
        off0 = 459 + (lane - 16)*3; off1 = off0 + 1; off2 = off0 + 2;
      }
    }

    if (tid < 256){
      S.ww_[tid] = DELTA_; S.usage[tid] = 0.0f; S.prec_[tid] = 0.0f;
      S.invn[tid] = 1.0f/(fsqrt_(64.0f*DELTA_*DELTA_) + DELTA_);
      #pragma unroll
      for (int r = 0; r < 4; ++r) S.rw_[r][tid] = DELTA_;
    }
    for (int i = tid; i < 4*264; i += 1024) ((bf16_t*)S.rwb)[i] = (bf16_t)DELTA_;
    for (int i = tid; i < 256*65; i += 1024) ((float*)S.smem)[i] = DELTA_;
    __syncthreads();

    // ---- pre-loop: wait for XI[0] (producer gen >= 3), load regs ----
    if (wv == 0){
      for (;;){
        unsigned f = flag_ld(flg + (size_t)lane*16);
        if (__all(f >= 3u)) break;
        __builtin_amdgcn_s_sleep(2);
      }
      __builtin_amdgcn_fence(__ATOMIC_ACQUIRE, "agent");
    }
    __syncthreads();
    float x0 = 0.0f, x1 = 0.0f, x2 = 0.0f;
    {
      const float* xp = XI + (size_t)b*480;
      if (off0 >= 0) x0 = xp[off0];
      if (off1 >= 0){ x1 = xp[off1]; x2 = xp[off2]; }
    }

    for (int t = 0; t < 32; ++t){
      // ---- R2: parse interface vector from registers ----
      if (wv < 4){
        float v = tanh_f(x0);
        float s = wred(v*v);
        float vn = v * frcp(fsqrt_(s) + DELTA_);
        #pragma unroll
        for (int g = 0; g < 4; ++g) S.u.a.rkn4r[g][lane][wv] = vn;
      } else if (wv == 4){
        float v = tanh_f(x0);
        float s = wred(v*v);
        S.wkn[lane] = v * frcp(fsqrt_(s) + DELTA_);
      } else if (wv == 5){ S.ev_[lane] = sigf(x0);
      } else if (wv == 6){ S.wvv[lane] = tanh_f(x0);
      } else if (wv == 7){
        if (lane < 4)        S.rs_[lane] = softplusf(x0);
        else if (lane == 4)  S.wsS = softplusf(x0);
        else if (lane < 9)   S.fg_[lane-5] = sigf(x0);
        else if (lane == 9)  S.agS = sigf(x0);
        else if (lane == 10) S.wgS = sigf(x0);
        else if (lane >= 16 && lane < 20){
          int r = lane - 16;
          float mx = fmaxf(x0, fmaxf(x1, x2));
          float e0 = __expf(x0-mx), e1 = __expf(x1-mx), e2 = __expf(x2-mx);
          float inv = frcp(e0+e1+e2);
          S.rm_[r][0]=e0*inv; S.rm_[r][1]=e1*inv; S.rm_[r][2]=e2*inv;
        }
      }
      __syncthreads();

      // ---- R3: usage update (tid<256) + write-content partials (all) ----
      if (tid < 256){
        int m = tid;
        float us = S.usage[m] + (1.0f - S.usage[m])*S.ww_[m];
        float psi = (1.0f - S.fg_[0]*S.rw_[0][m]) * (1.0f - S.fg_[1]*S.rw_[1][m])
                  * (1.0f - S.fg_[2]*S.rw_[2][m]) * (1.0f - S.fg_[3]*S.rw_[3][m]);
        us *= psi;
        S.usage[m] = us;
        S.u.a.uu[m] = DELTA_ + (1.0f - DELTA_)*us;
      }
      { float acc = 0.0f;
        #pragma unroll
        for (int it = 0; it < 16; ++it){
          int w = q4*16 + it;
          acc += S.smem[mQ][w] * S.wkn[w];
        }
        S.u.a.p4cT[q4][mQ] = acc; }
      __syncthreads();

      // ---- R4: wave0 wcw softmax ; tid>=512: split rank counts ----
      if (wv == 0){
        #pragma unroll
        for (int z = 0; z < 4; ++z){
          int m = z*64 + lane;
          S.u.a.wcw[m] = S.wsS * (S.u.a.p4cT[0][m] + S.u.a.p4cT[1][m]
                                + S.u.a.p4cT[2][m] + S.u.a.p4cT[3][m]) * S.invn[m];
        }
        softmax256_wave(S.u.a.wcw, lane);
      } else if (tid >= 512){
        const int idx = tid - 512;
        const int i = idx & 255, half = idx >> 8;
        const float ui = S.u.a.uu[i];
        int cnt = 0;
        #pragma unroll 8
        for (int k = 0; k < 32; ++k){
          f32x4 u4 = *(const f32x4*)&S.u.a.uu[half*128 + k*4];
          #pragma unroll
          for (int z = 0; z < 4; ++z){
            int j = half*128 + k*4 + z; float uj = u4[z];
            cnt += (uj < ui || (uj == ui && j < i)) ? 1 : 0;
          }
        }
        S.u.a.rankP[half][i] = cnt;
      }
      __syncthreads();

      // ---- R5a: combine ranks + scatter su (tid<256) ----
      if (tid < 256){
        int rank = S.u.a.rankP[0][tid] + S.u.a.rankP[1][tid];
        S.u.a.rank_[tid] = rank;
        S.u.a.su[rank] = S.u.a.uu[tid];
      }
      __syncthreads();

      // ---- R5b: exclusive product scan of su -> scanA (wave 0) ----
      if (wv == 0){
        int base = lane*4;
        float v0 = S.u.a.su[base], v1 = S.u.a.su[base+1], v2 = S.u.a.su[base+2];
        float p1 = v0*v1, p2 = p1*v2, p3 = p2*S.u.a.su[base+3];
        float sc = p3;
        #pragma unroll
        for (int off = 1; off < 64; off <<= 1){
          float n = __shfl_up(sc, off, 64);
          if (lane >= off) sc *= n;
        }
        float exch = __shfl_up(sc, 1, 64);
        if (lane == 0) exch = 1.0f;
        S.u.a.scanA[base] = exch; S.u.a.scanA[base+1] = exch*v0;
        S.u.a.scanA[base+2] = exch*p1; S.u.a.scanA[base+3] = exch*p2;
      }
      __syncthreads();

      // ---- R7: ww + mem erase/write (smem) + partials (thread = (mQ,q4)) --
      { float al = (1.0f - S.u.a.uu[mQ]) * S.u.a.scanA[S.u.a.rank_[mQ]];
        float wm = S.wgS*(S.agS*al + (1.0f - S.agS)*S.u.a.wcw[mQ]);
        if (q4 == 0) S.ww_[mQ] = wm;
        float s2 = 0.0f, sr0 = 0.0f, sr1 = 0.0f, sr2 = 0.0f, sr3 = 0.0f;
        #pragma unroll
        for (int it = 0; it < 16; ++it){
          int w = q4*16 + it;
          float mn = S.smem[mQ][w]*(1.0f - wm*S.ev_[w]) + wm*S.wvv[w];
          S.smem[mQ][w] = mn;
          s2 += mn*mn;
          f32x4 rk = *(const f32x4*)&S.u.a.rkn4r[q4][w][0];
          sr0 += mn*rk[0]; sr1 += mn*rk[1]; sr2 += mn*rk[2]; sr3 += mn*rk[3];
        }
        S.u.a.p5cT[0][q4][mQ] = s2;
        S.u.a.p5cT[1][q4][mQ] = sr0; S.u.a.p5cT[2][q4][mQ] = sr1;
        S.u.a.p5cT[3][q4][mQ] = sr2; S.u.a.p5cT[4][q4][mQ] = sr3; }
      __syncthreads();

      // ---- R8+R9a: norm/rcw-pre (tid<256) + wwsum (wv4) + link row update -
      if (tid < 256){
        int m = tid;
        float s2 = S.u.a.p5cT[0][0][m] + S.u.a.p5cT[0][1][m]
                 + S.u.a.p5cT[0][2][m] + S.u.a.p5cT[0][3][m];
        float inv = frcp(fsqrt_(s2) + DELTA_);
        S.invn[m] = inv;
        #pragma unroll
        for (int r = 0; r < 4; ++r){
          float sr = S.u.a.p5cT[r+1][0][m] + S.u.a.p5cT[r+1][1][m]
                   + S.u.a.p5cT[r+1][2][m] + S.u.a.p5cT[r+1][3][m];
          S.rcw_[r][m] = S.rs_[r]*sr*inv;
        }
      } else if (wv == 4){
        float s = wred(S.ww_[lane] + S.ww_[64+lane] + S.ww_[128+lane] + S.ww_[192+lane]);
        if (lane == 0) S.wwsumS = s;
      }
      // R9a: link row update + fwd via MFMA (16 waves x 16 rows)
      { const float wown = S.ww_[orow], pown = S.prec_[orow];
        const float alpha = 1.0f - wown;
        f32x4 facc = {0,0,0,0};
        #pragma unroll
        for (int ch = 0; ch < 8; ++ch){
          const int cbase = ch*32 + quad*8;
          bf16x8 rwf = *(const bf16x8*)&S.rwb[li & 3][cbase];
          f32x4 wA = *(const f32x4*)&S.ww_[cbase];
          f32x4 wB = *(const f32x4*)&S.ww_[cbase+4];
          f32x4 pA = *(const f32x4*)&S.prec_[cbase];
          f32x4 pB = *(const f32x4*)&S.prec_[cbase+4];
          float wcf[8] = {wA[0],wA[1],wA[2],wA[3],wB[0],wB[1],wB[2],wB[3]};
          float pcf[8] = {pA[0],pA[1],pA[2],pA[3],pB[0],pB[1],pB[2],pB[3]};
          bf16x8 rl = rowL[ch];
          #pragma unroll
          for (int jj = 0; jj < 8; ++jj){
            const int c = cbase + jj;
            float s = alpha - wcf[jj];
            float vr = s*(float)rl[jj] + wown*pcf[jj];
            if (c == orow) vr = 0.0f;
            rl[jj] = (bf16_t)vr;
          }
          rowL[ch] = rl;
          facc = __builtin_amdgcn_mfma_f32_16x16x32_bf16(rl, rwf, facc, 0, 0, 0);
        }
        if (li < 4){
          #pragma unroll
          for (int z = 0; z < 4; ++z) S.fwd_[li][wv*16 + quad*4 + z] = facc[z];
        }
      }
      __syncthreads();   // all scratch reads (p5cT etc.) done -> tls may write

      // ---- R9b: bwd via 8 tls sub-phases (2 waves co-write 32 rows) ----
      { f32x4 bacc = {0,0,0,0};
        #pragma unroll 1
        for (int sub = 0; sub < 8; ++sub){
          if ((wv >> 1) == sub){
            #pragma unroll
            for (int ch = 0; ch < 8; ++ch)
              *(bf16x8*)&S.u.tls[(wv & 1)*16 + li][ch*32 + quad*8] = rowL[ch];
          }
          __syncthreads();
          { bf16x8 rwf = *(const bf16x8*)&S.rwb[li & 3][sub*32 + quad*8];
            const int x = wv*16 + li;
            bf16x8 cl;
            #pragma unroll
            for (int z = 0; z < 8; ++z) cl[z] = S.u.tls[quad*8 + z][x];
            bacc = __builtin_amdgcn_mfma_f32_16x16x32_bf16(rwf, cl, bacc, 0, 0, 0);
          }
          __syncthreads();
        }
        if (quad == 0){
          #pragma unroll
          for (int z = 0; z < 4; ++z) S.bwd_[z][wv*16 + li] = bacc[z];
        }
      }
      __syncthreads();

      // ---- R10: rcw softmax (wv<4) ; precedence (512..767) ; poll (wv15) --
      if (wv < 4) softmax256_wave(S.rcw_[wv], lane);
      else if (tid >= 512 && tid < 768){
        int m = tid - 512;
        float p = (1.0f - S.wwsumS)*S.prec_[m] + S.ww_[m];
        S.prec_[m] = p;
      } else if (wv == 15 && t < 31){
        const unsigned tgt = (unsigned)(t + 4);
        for (;;){
          unsigned f = flag_ld(flg + (size_t)lane*16);
          if (__all(f >= tgt)) break;
          __builtin_amdgcn_s_sleep(2);
        }
        __builtin_amdgcn_fence(__ATOMIC_ACQUIRE, "agent");
      }
      __syncthreads();

      // ---- R11: prefetch XI(t+1) + new read weights (1 elem/thread) ----
      if (t < 31 && off0 >= 0){
        const float* xp = XI + ((size_t)(t+1)*64 + b)*480;
        x0 = xp[off0];
        if (off1 >= 0){ x1 = xp[off1]; x2 = xp[off2]; }
      }
      { const int r = tid >> 8, m = tid & 255;
        float v = S.rm_[r][0]*S.bwd_[r][m] + S.rm_[r][1]*S.fwd_[r][m] + S.rm_[r][2]*S.rcw_[r][m];
        S.rw_[r][m] = v;
        S.rw4[m][r] = v;
        S.rwb[r][m] = (bf16_t)v;
      }
      __syncthreads();

      // ---- R12: read vectors: wave-per-16-rows ----
      { float r0 = 0, r1 = 0, r2 = 0, r3 = 0;
        #pragma unroll
        for (int k = 0; k < 16; ++k){
          int m = wv*16 + k;
          f32x4 r4 = *(const f32x4*)&S.rw4[m][0];
          float mv = S.smem[m][lane];
          r0 += r4[0]*mv; r1 += r4[1]*mv; r2 += r4[2]*mv; r3 += r4[3]*mv;
        }
        S.u.a.rvp[wv][0][lane] = r0; S.u.a.rvp[wv][1][lane] = r1;
        S.u.a.rvp[wv][2][lane] = r2; S.u.a.rvp[wv][3][lane] = r3; }
      __syncthreads();

      // ---- R13: combine + store ----
      if (tid < 256){
        const int w = tid & 63, r = tid >> 6;
        float v = 0.0f;
        #pragma unroll
        for (int c = 0; c < 16; ++c) v += S.u.a.rvp[c][r][w];
        RVEC[((size_t)t*64 + b)*256 + tid] = v;
      }
      // no trailing barrier: R13 reads rvp (R12, barrier'd); next-step R2
      // writes (rkn4r) are separated from R13's rvp reads by R2..R9a
      // barriers before tls/rvp can be overwritten again.
    }
  }
}

// ---------------------------------------------------------------------------
__global__ void k_tanhy(const bf16_t* __restrict__ outseq, const float* __restrict__ RVEC,
                        bf16_t* __restrict__ Y){
  const int n = 2048*768;
  for (int i = blockIdx.x*blockDim.x + threadIdx.x; i < n; i += gridDim.x*blockDim.x){
    int row = i / 768, j = i - row*768;
    float v = (j < 512) ? (float)outseq[(size_t)row*512 + j] : RVEC[(size_t)row*256 + (j - 512)];
    Y[i] = (bf16_t)tanh_f(v);
  }
}

__global__ __launch_bounds__(256,1) void k_out(
    const bf16_t* __restrict__ Y, const bf16_t* __restrict__ Woutb,
    const float* __restrict__ boutf, void* __restrict__ dout,
    const int* __restrict__ flag)
{
  const int mf = *flag;
  const int mt = blockIdx.x;          // 0..127
  const int tid = threadIdx.x, lane = tid & 63, wv = tid >> 6;
  const int nt = blockIdx.y*4 + wv;   // 0..15
  const int m16 = lane & 15, q = lane >> 4;
  const int o = nt*16 + m16;
  float bv = boutf[o];
  f32x4 acc = {bv,bv,bv,bv};
  const bf16_t* arow = Y + (size_t)(mt*16 + m16)*768 + q*8;
  const bf16_t* brow = Woutb + (size_t)o*768 + q*8;
  for (int kt = 0; kt < 24; ++kt){
    acc = __builtin_amdgcn_mfma_f32_16x16x32_bf16(
        *(const bf16x8*)(arow + kt*32), *(const bf16x8*)(brow + kt*32), acc, 0, 0, 0);
  }
  #pragma unroll
  for (int v = 0; v < 4; ++v){
    int row = mt*16 + q*4 + v;        // = t*64 + b
    int b = row & 63, t = row >> 6;
    size_t idx = ((size_t)b*T_ + t)*256 + o;
    if (mf) ((float*)dout)[idx] = acc[v];
    else    ((bf16_t*)dout)[idx] = (bf16_t)acc[v];
  }
}

// ---------------------------------------------------------------------------
extern "C" void kernel_launch(void* const* d_in, const int* in_sizes, int n_in,
                              void* d_out, int out_size, void* d_ws, size_t ws_size,
                              hipStream_t stream)
{
  char* ws = (char*)d_ws;
  bf16_t* H0SEQ  = (bf16_t*)(ws + OFF_H0SEQ);
  bf16_t* OUTSEQ = (bf16_t*)(ws + OFF_OUTSEQ);
  bf16_t* H0BUF  = (bf16_t*)(ws + OFF_H0BUF);
  bf16_t* H1BUF  = (bf16_t*)(ws + OFF_H1BUF);
  float*  XI     = (float*) (ws + OFF_XI);
  float*  RVEC   = (float*) (ws + OFF_RVEC);
  bf16_t* YBF    = (bf16_t*)(ws + OFF_YBF);
  unsigned* BAR  = (unsigned*)(ws + OFF_BAR);
  int*    FLAG   = (int*)   (ws + OFF_BAR + 8);
  bf16_t* XB     = (bf16_t*)(ws + OFF_XB);
  bf16_t* H0B    = (bf16_t*)(ws + OFF_H0B);
  bf16_t* W0     = (bf16_t*)(ws + OFF_W0);
  bf16_t* W1     = (bf16_t*)(ws + OFF_W1);
  bf16_t* W2     = (bf16_t*)(ws + OFF_W2);
  bf16_t* W3     = (bf16_t*)(ws + OFF_W3);
  bf16_t* WIFP   = (bf16_t*)(ws + OFF_WIF);
  bf16_t* WOUTB  = (bf16_t*)(ws + OFF_WOUTB);
  float*  BS0    = (float*) (ws + OFF_BS0);
  float*  BS1    = (float*) (ws + OFF_BS1);
  float*  BIFP   = (float*) (ws + OFF_BIF);
  float*  BOUTF  = (float*) (ws + OFF_BOUTF);
  unsigned* FLG  = (unsigned*)(ws + OFF_FLG);

  k_detect<<<1, 256, 0, stream>>>((const unsigned short*)d_in[0], FLAG, BAR, FLG);
  k_convert<<<dim3(256, 9), 256, 0, stream>>>(
      d_in[0], d_in[1], d_in[2], d_in[3], d_in[4], d_in[5], d_in[6],
      d_in[7], d_in[8], d_in[9], d_in[10], d_in[11], d_in[12], d_in[13],
      XB, H0B, H0BUF, H1BUF, W0, W1, W2, W3, WIFP, WOUTB,
      BS0, BS1, BIFP, BOUTF, FLAG);
  k_main<<<128, 1024, 0, stream>>>(XB, H0B, W0, W1, W2, W3, BS0, BS1,
                                   WIFP, BIFP, H0BUF, H1BUF, H0SEQ, OUTSEQ,
                                   XI, RVEC, FLG);
  k_tanhy<<<512, 256, 0, stream>>>(OUTSEQ, RVEC, YBF);
  k_out<<<dim3(128, 4), 256, 0, stream>>>(YBF, WOUTB, BOUTF, d_out, FLAG);
}